// Round 1
// baseline (884.872 us; speedup 1.0000x reference)
//
#include <hip/hip_runtime.h>
#include <math.h>

#define SQ 2048      // seq len
#define DE 512       // d_embedding
#define DH 64        // d_head
#define CW 128       // half-window
#define W2 256       // window width
#define NH 8         // heads

// ---------------- prep: copy x -> cur, transpose Wq/Wk/Wvd to [h][e][c] ----------------
__global__ __launch_bounds__(256) void prep_kernel(
    const float* __restrict__ x, const float* __restrict__ Wq,
    const float* __restrict__ Wk, const float* __restrict__ Wvd,
    float* __restrict__ cur, float* __restrict__ WTq,
    float* __restrict__ WTk, float* __restrict__ WTv) {
  int i = blockIdx.x * 256 + threadIdx.x;
  if (i < SQ * DE) cur[i] = x[i];
  if (i < NH * DE * DH) {
    int c = i & 63;           // dh index
    int e = (i >> 6) & 511;   // embedding index
    int h = i >> 15;
    int src = (h * DH + c) * DE + e;
    WTq[i] = Wq[src];
    WTk[i] = Wk[src];
    WTv[i] = Wvd[src];
  }
}

// ---------------- qkv: q/k/v[s, dh] = cur[s, :] . WT[:, dh] ----------------
// 256 blocks, 8 rows each; 4 waves x 2 rows; lane = output column.
__global__ __launch_bounds__(256) void qkv_kernel(
    const float* __restrict__ cur,
    const float* __restrict__ WTq, const float* __restrict__ WTk,
    const float* __restrict__ WTv,
    float* __restrict__ q, float* __restrict__ k, float* __restrict__ v) {
  __shared__ float curL[8][DE];  // 16 KB
  int tid = threadIdx.x;
  int j0 = blockIdx.x * 8;

  const float4* src = (const float4*)(cur + (size_t)j0 * DE);
  float4* dst = (float4*)(&curL[0][0]);
#pragma unroll
  for (int t = 0; t < 4; t++) dst[tid + 256 * t] = src[tid + 256 * t];
  __syncthreads();

  int lane = tid & 63;
  int wv = tid >> 6;
  int r0 = 2 * wv, r1 = 2 * wv + 1;
  float aq0 = 0, aq1 = 0, ak0 = 0, ak1 = 0, av0 = 0, av1 = 0;
  for (int e = 0; e < DE; e++) {
    float wq = WTq[e * DH + lane];
    float wk = WTk[e * DH + lane];
    float wvv = WTv[e * DH + lane];
    float x0 = curL[r0][e], x1 = curL[r1][e];
    aq0 += x0 * wq; aq1 += x1 * wq;
    ak0 += x0 * wk; ak1 += x1 * wk;
    av0 += x0 * wvv; av1 += x1 * wvv;
  }
  q[(j0 + r0) * DH + lane] = aq0; q[(j0 + r1) * DH + lane] = aq1;
  k[(j0 + r0) * DH + lane] = ak0; k[(j0 + r1) * DH + lane] = ak1;
  v[(j0 + r0) * DH + lane] = av0; v[(j0 + r1) * DH + lane] = av1;
}

// ---------------- attn: windowed attention + upproj + renorm + residual ----------------
// 256 blocks x 8 queries. Window union offsets: goff in [0, 263); key g = j0-128+goff;
// for query jq, score position p = goff - jq (valid 0<=p<256).
__global__ __launch_bounds__(256) void attn_kernel(
    float* cur,  // read + write in place (own rows only)
    const float* __restrict__ q, const float* __restrict__ k,
    const float* __restrict__ v, const float* __restrict__ Wvu,
    float* __restrict__ out, int last) {
  __shared__ float qL[8][DH];       // 2 KB
  __shared__ float sL[8][W2];       // 8 KB  (scores -> softmax weights in place)
  __shared__ float pL[4][8][DH];    // 8 KB  (per-wave delta partials)
  __shared__ float dL[8][DH];       // 2 KB
  __shared__ float yL[8][DE];       // 16 KB

  int tid = threadIdx.x;
  int lane = tid & 63;
  int wv = tid >> 6;
  int j0 = blockIdx.x * 8;

  // load q rows
  {
    const float* qs = q + (size_t)j0 * DH;
    ((float*)qL)[tid] = qs[tid];
    ((float*)qL)[tid + 256] = qs[tid + 256];
  }
  __syncthreads();

  // ---- scores: each thread owns union offsets goff = tid, tid+256 ----
  for (int goff = tid; goff < 263; goff += 256) {
    int g = j0 - CW + goff;
    bool valid = (g >= 0 && g < SQ);
    int gc = valid ? g : 0;
    float acc[8] = {0, 0, 0, 0, 0, 0, 0, 0};
    const float4* krow = (const float4*)(k + (size_t)gc * DH);
#pragma unroll
    for (int ch = 0; ch < 16; ch++) {
      float4 kf = krow[ch];
#pragma unroll
      for (int jq = 0; jq < 8; jq++) {
        float4 qf = ((const float4*)qL[jq])[ch];
        acc[jq] += qf.x * kf.x + qf.y * kf.y + qf.z * kf.z + qf.w * kf.w;
      }
    }
#pragma unroll
    for (int jq = 0; jq < 8; jq++) {
      int p = goff - jq;
      if (p >= 0 && p < W2) sL[jq][p] = valid ? acc[jq] * 0.125f : -INFINITY;
    }
  }
  __syncthreads();

  // ---- softmax per query row (wave per row, 2 rows per wave) ----
  for (int jj = 0; jj < 2; jj++) {
    int jq = wv + 4 * jj;
    float m = -INFINITY;
#pragma unroll
    for (int t4 = 0; t4 < 4; t4++) m = fmaxf(m, sL[jq][lane + 64 * t4]);
#pragma unroll
    for (int off = 32; off; off >>= 1) m = fmaxf(m, __shfl_xor(m, off));
    float ex[4];
    float ssum = 0;
#pragma unroll
    for (int t4 = 0; t4 < 4; t4++) {
      ex[t4] = __expf(sL[jq][lane + 64 * t4] - m);
      ssum += ex[t4];
    }
#pragma unroll
    for (int off = 32; off; off >>= 1) ssum += __shfl_xor(ssum, off);
    float inv = 1.0f / ssum;
#pragma unroll
    for (int t4 = 0; t4 < 4; t4++) sL[jq][lane + 64 * t4] = ex[t4] * inv;
  }
  __syncthreads();

  // ---- delta = w . v_window ; waves split the union-g range ----
  {
    float dacc[8] = {0, 0, 0, 0, 0, 0, 0, 0};
    int gbeg = 66 * wv;
    int gend = gbeg + 66; if (gend > 263) gend = 263;
    for (int goff = gbeg; goff < gend; goff++) {
      int g = j0 - CW + goff;
      int gc = g < 0 ? 0 : (g >= SQ ? SQ - 1 : g);
      float vvv = v[(size_t)gc * DH + lane];
#pragma unroll
      for (int jq = 0; jq < 8; jq++) {
        int p = goff - jq;
        if (p >= 0 && p < W2) dacc[jq] += sL[jq][p] * vvv;
      }
    }
#pragma unroll
    for (int jq = 0; jq < 8; jq++) pL[wv][jq][lane] = dacc[jq];
  }
  __syncthreads();
  for (int i = tid; i < 8 * DH; i += 256) {
    int jq = i >> 6, d = i & 63;
    dL[jq][d] = pL[0][jq][d] + pL[1][jq][d] + pL[2][jq][d] + pL[3][jq][d];
  }
  __syncthreads();

  // ---- upproj + residual: y[jq][e] = cur[j][e] + dL[jq] . Wvu[e][:] ----
  for (int half = 0; half < 2; half++) {
    int e = tid + 256 * half;
    float acc[8] = {0, 0, 0, 0, 0, 0, 0, 0};
    const float4* wrow = (const float4*)(Wvu + (size_t)e * DH);
#pragma unroll
    for (int ch = 0; ch < 16; ch++) {
      float4 wf = wrow[ch];
#pragma unroll
      for (int jq = 0; jq < 8; jq++) {
        float4 df = ((const float4*)dL[jq])[ch];
        acc[jq] += df.x * wf.x + df.y * wf.y + df.z * wf.z + df.w * wf.w;
      }
    }
#pragma unroll
    for (int jq = 0; jq < 8; jq++)
      yL[jq][e] = cur[(size_t)(j0 + jq) * DE + e] + acc[jq];
  }
  __syncthreads();

  // ---- renorm: m1 = mean(y); y2 = y/m1; m2 = mean(y2); sd = std(y2, ddof=1);
  //      result = (y2-m2)/sd + m2 ; cur += result ; last head: out = cur/8 ----
  for (int jj = 0; jj < 2; jj++) {
    int jq = wv + 4 * jj;
    int j = j0 + jq;
    float s = 0;
#pragma unroll
    for (int t8 = 0; t8 < 8; t8++) s += yL[jq][lane + 64 * t8];
#pragma unroll
    for (int off = 32; off; off >>= 1) s += __shfl_xor(s, off);
    float m1 = s * (1.0f / 512.0f);
    float inv_m1 = 1.0f / m1;
    float y2[8];
    float s2 = 0, s2q = 0;
#pragma unroll
    for (int t8 = 0; t8 < 8; t8++) {
      y2[t8] = yL[jq][lane + 64 * t8] * inv_m1;
      s2 += y2[t8];
      s2q += y2[t8] * y2[t8];
    }
#pragma unroll
    for (int off = 32; off; off >>= 1) {
      s2 += __shfl_xor(s2, off);
      s2q += __shfl_xor(s2q, off);
    }
    float m2 = s2 * (1.0f / 512.0f);
    float var = (s2q - 512.0f * m2 * m2) * (1.0f / 511.0f);
    float isd = 1.0f / sqrtf(var);
#pragma unroll
    for (int t8 = 0; t8 < 8; t8++) {
      int e = lane + 64 * t8;
      float o = (y2[t8] - m2) * isd + m2;
      float nc = cur[(size_t)j * DE + e] + o;
      cur[(size_t)j * DE + e] = nc;
      if (last) out[(size_t)j * DE + e] = nc * (1.0f / NH);
    }
  }
}

extern "C" void kernel_launch(void* const* d_in, const int* in_sizes, int n_in,
                              void* d_out, int out_size, void* d_ws, size_t ws_size,
                              hipStream_t stream) {
  const float* x   = (const float*)d_in[0];
  const float* Wq  = (const float*)d_in[1];
  const float* Wk  = (const float*)d_in[2];
  const float* Wvd = (const float*)d_in[3];
  const float* Wvu = (const float*)d_in[4];
  float* out = (float*)d_out;

  float* ws  = (float*)d_ws;
  float* cur = ws;                    // SQ*DE
  float* q   = cur + SQ * DE;         // SQ*DH
  float* k   = q + SQ * DH;
  float* v   = k + SQ * DH;
  float* WTq = v + SQ * DH;           // NH*DE*DH each
  float* WTk = WTq + NH * DE * DH;
  float* WTv = WTk + NH * DE * DH;

  prep_kernel<<<4096, 256, 0, stream>>>(x, Wq, Wk, Wvd, cur, WTq, WTk, WTv);
  for (int h = 0; h < NH; h++) {
    const size_t wo = (size_t)h * DE * DH;
    qkv_kernel<<<SQ / 8, 256, 0, stream>>>(cur, WTq + wo, WTk + wo, WTv + wo,
                                           q, k, v);
    attn_kernel<<<SQ / 8, 256, 0, stream>>>(cur, q, k, v, Wvu + wo, out,
                                            h == NH - 1 ? 1 : 0);
  }
}

// Round 2
// 696.335 us; speedup vs baseline: 1.2708x; 1.2708x over previous
//
#include <hip/hip_runtime.h>
#include <math.h>

#define SQ 2048      // seq len
#define DE 512       // d_embedding
#define DH 64        // d_head
#define CW 128       // half-window
#define W2 256       // window width
#define NH 8         // heads
#define NQ 4         // queries per block
#define UW (W2 + NQ - 1)  // union window width = 259

// ---------------- prep: copy x -> cur, transpose Wq/Wk/Wvd to [h][e][c] ----------------
__global__ __launch_bounds__(256) void prep_kernel(
    const float* __restrict__ x, const float* __restrict__ Wq,
    const float* __restrict__ Wk, const float* __restrict__ Wvd,
    float* __restrict__ cur, float* __restrict__ WTq,
    float* __restrict__ WTk, float* __restrict__ WTv) {
  int i = blockIdx.x * 256 + threadIdx.x;
  if (i < SQ * DE) cur[i] = x[i];
  if (i < NH * DE * DH) {
    int c = i & 63;           // dh index
    int e = (i >> 6) & 511;   // embedding index
    int h = i >> 15;
    int src = (h * DH + c) * DE + e;
    WTq[i] = Wq[src];
    WTk[i] = Wk[src];
    WTv[i] = Wvd[src];
  }
}

// ---------------- qkv0: q/k/v for head 0 straight from x ----------------
// 512 blocks x 4 rows; waves split e-range (weights read once/block), LDS reduce.
__global__ __launch_bounds__(256, 2) void qkv0_kernel(
    const float* __restrict__ x,
    const float* __restrict__ WTq, const float* __restrict__ WTk,
    const float* __restrict__ WTv,
    float* __restrict__ q, float* __restrict__ k, float* __restrict__ v) {
  __shared__ float xL[NQ][DE];        // 8 KB
  __shared__ float qP[4][3][NQ][DH];  // 12 KB
  int tid = threadIdx.x, lane = tid & 63, wv = tid >> 6;
  int j0 = blockIdx.x * NQ;

  const float4* src = (const float4*)(x + (size_t)j0 * DE);
  float4* dst = (float4*)xL;
  dst[tid] = src[tid];
  dst[tid + 256] = src[tid + 256];
  __syncthreads();

  float aq[NQ] = {0, 0, 0, 0}, ak[NQ] = {0, 0, 0, 0}, av[NQ] = {0, 0, 0, 0};
  int e0 = wv * 128;
  for (int e = e0; e < e0 + 128; e++) {
    float wq = WTq[e * DH + lane];
    float wk = WTk[e * DH + lane];
    float wvv = WTv[e * DH + lane];
#pragma unroll
    for (int r = 0; r < NQ; r++) {
      float xr = xL[r][e];
      aq[r] += xr * wq; ak[r] += xr * wk; av[r] += xr * wvv;
    }
  }
#pragma unroll
  for (int r = 0; r < NQ; r++) {
    qP[wv][0][r][lane] = aq[r];
    qP[wv][1][r][lane] = ak[r];
    qP[wv][2][r][lane] = av[r];
  }
  __syncthreads();
  for (int i = tid; i < 3 * NQ * DH; i += 256) {
    int o = i >> 8;              // 0..2 (NQ*DH = 256)
    int rem = i & 255;
    int r = rem >> 6, c = rem & 63;
    float s = qP[0][o][r][c] + qP[1][o][r][c] + qP[2][o][r][c] + qP[3][o][r][c];
    float* dp = (o == 0 ? q : (o == 1 ? k : v));
    dp[(size_t)(j0 + r) * DH + c] = s;
  }
}

// ---------------- fused: attn(head h) [+ qkv(head h+1)] ----------------
// flags bit0: last head -> write out = cur/8 ; bit1: compute next-head qkv
__global__ __launch_bounds__(256, 2) void fused_kernel(
    float* cur,
    const float* __restrict__ q, const float* __restrict__ k,
    const float* __restrict__ v, const float* __restrict__ Wvu,
    const float* __restrict__ WTqn, const float* __restrict__ WTkn,
    const float* __restrict__ WTvn,
    float* __restrict__ qn, float* __restrict__ kn, float* __restrict__ vn,
    float* __restrict__ out, int flags) {
  __shared__ float qL[NQ][DH];        // 1 KB
  __shared__ float sL[NQ][W2];        // 4 KB
  __shared__ float pL[4][NQ][DH];     // 4 KB
  __shared__ float dL[NQ][DH];        // 1 KB
  __shared__ float yL[NQ][DE];        // 8 KB (y, then new-cur)
  __shared__ float qP[4][3][NQ][DH];  // 12 KB

  int tid = threadIdx.x, lane = tid & 63, wv = tid >> 6;
  int j0 = blockIdx.x * NQ;

  // load q rows (NQ*DH = 256 floats)
  ((float*)qL)[tid] = q[(size_t)j0 * DH + tid];
  __syncthreads();

  // ---- scores over union window ----
  for (int goff = tid; goff < UW; goff += 256) {
    int g = j0 - CW + goff;
    bool valid = (g >= 0 && g < SQ);
    int gc = valid ? g : 0;
    float acc[NQ] = {0, 0, 0, 0};
    const float4* krow = (const float4*)(k + (size_t)gc * DH);
#pragma unroll
    for (int ch = 0; ch < 16; ch++) {
      float4 kf = krow[ch];
#pragma unroll
      for (int r = 0; r < NQ; r++) {
        float4 qf = ((const float4*)qL[r])[ch];
        acc[r] += qf.x * kf.x + qf.y * kf.y + qf.z * kf.z + qf.w * kf.w;
      }
    }
#pragma unroll
    for (int r = 0; r < NQ; r++) {
      int p = goff - r;
      if (p >= 0 && p < W2) sL[r][p] = valid ? acc[r] * 0.125f : -INFINITY;
    }
  }
  __syncthreads();

  // ---- softmax: wave wv owns row wv ----
  {
    int r = wv;
    float m = -INFINITY;
#pragma unroll
    for (int t = 0; t < 4; t++) m = fmaxf(m, sL[r][lane + 64 * t]);
#pragma unroll
    for (int off = 32; off; off >>= 1) m = fmaxf(m, __shfl_xor(m, off));
    float ex[4], ss = 0;
#pragma unroll
    for (int t = 0; t < 4; t++) {
      ex[t] = __expf(sL[r][lane + 64 * t] - m);
      ss += ex[t];
    }
#pragma unroll
    for (int off = 32; off; off >>= 1) ss += __shfl_xor(ss, off);
    float inv = 1.0f / ss;
#pragma unroll
    for (int t = 0; t < 4; t++) sL[r][lane + 64 * t] = ex[t] * inv;
  }
  __syncthreads();

  // ---- delta = w . v_window ; waves split union range; v loads coalesced ----
  {
    float dacc[NQ] = {0, 0, 0, 0};
    int gbeg = 65 * wv, gend = gbeg + 65;
    if (gend > UW) gend = UW;
    for (int goff = gbeg; goff < gend; goff++) {
      int g = j0 - CW + goff;
      int gc = g < 0 ? 0 : (g >= SQ ? SQ - 1 : g);
      float vv = v[(size_t)gc * DH + lane];
#pragma unroll
      for (int r = 0; r < NQ; r++) {
        int p = goff - r;
        if (p >= 0 && p < W2) dacc[r] += sL[r][p] * vv;
      }
    }
#pragma unroll
    for (int r = 0; r < NQ; r++) pL[wv][r][lane] = dacc[r];
  }
  __syncthreads();
  if (tid < NQ * DH) {
    int r = tid >> 6, c = tid & 63;
    dL[r][c] = pL[0][r][c] + pL[1][r][c] + pL[2][r][c] + pL[3][r][c];
  }
  __syncthreads();

  // ---- upproj + residual into yL ----
#pragma unroll
  for (int half = 0; half < 2; half++) {
    int e = tid + 256 * half;
    float acc[NQ] = {0, 0, 0, 0};
    const float4* wrow = (const float4*)(Wvu + (size_t)e * DH);
#pragma unroll
    for (int ch = 0; ch < 16; ch++) {
      float4 wf = wrow[ch];
#pragma unroll
      for (int r = 0; r < NQ; r++) {
        float4 df = ((const float4*)dL[r])[ch];
        acc[r] += df.x * wf.x + df.y * wf.y + df.z * wf.z + df.w * wf.w;
      }
    }
#pragma unroll
    for (int r = 0; r < NQ; r++)
      yL[r][e] = cur[(size_t)(j0 + r) * DE + e] + acc[r];
  }
  __syncthreads();

  // ---- renorm + residual update; wave wv owns row wv ----
  {
    int r = wv;
    size_t jrow = (size_t)(j0 + r) * DE;
    float s = 0;
#pragma unroll
    for (int t = 0; t < 8; t++) s += yL[r][lane + 64 * t];
#pragma unroll
    for (int off = 32; off; off >>= 1) s += __shfl_xor(s, off);
    float inv_m1 = 512.0f / s;  // 1/m1
    float y2[8], s2 = 0, s2q = 0;
#pragma unroll
    for (int t = 0; t < 8; t++) {
      y2[t] = yL[r][lane + 64 * t] * inv_m1;
      s2 += y2[t];
      s2q += y2[t] * y2[t];
    }
#pragma unroll
    for (int off = 32; off; off >>= 1) {
      s2 += __shfl_xor(s2, off);
      s2q += __shfl_xor(s2q, off);
    }
    float m2 = s2 * (1.0f / 512.0f);
    float var = (s2q - 512.0f * m2 * m2) * (1.0f / 511.0f);
    float isd = 1.0f / sqrtf(var);
#pragma unroll
    for (int t = 0; t < 8; t++) {
      int e = lane + 64 * t;
      float o = (y2[t] - m2) * isd + m2;
      float nc = cur[jrow + e] + o;
      cur[jrow + e] = nc;
      yL[r][e] = nc;  // new cur row for next-head qkv
      if (flags & 1) out[jrow + e] = nc * (1.0f / NH);
    }
  }
  __syncthreads();

  // ---- qkv for next head from LDS new-cur rows ----
  if (flags & 2) {
    float aq[NQ] = {0, 0, 0, 0}, ak[NQ] = {0, 0, 0, 0}, av[NQ] = {0, 0, 0, 0};
    int e0 = wv * 128;
    for (int e = e0; e < e0 + 128; e++) {
      float wq = WTqn[e * DH + lane];
      float wk = WTkn[e * DH + lane];
      float wvv = WTvn[e * DH + lane];
#pragma unroll
      for (int r = 0; r < NQ; r++) {
        float xr = yL[r][e];
        aq[r] += xr * wq; ak[r] += xr * wk; av[r] += xr * wvv;
      }
    }
#pragma unroll
    for (int r = 0; r < NQ; r++) {
      qP[wv][0][r][lane] = aq[r];
      qP[wv][1][r][lane] = ak[r];
      qP[wv][2][r][lane] = av[r];
    }
    __syncthreads();
    for (int i = tid; i < 3 * NQ * DH; i += 256) {
      int o = i >> 8;
      int rem = i & 255;
      int r = rem >> 6, c = rem & 63;
      float s = qP[0][o][r][c] + qP[1][o][r][c] + qP[2][o][r][c] + qP[3][o][r][c];
      float* dp = (o == 0 ? qn : (o == 1 ? kn : vn));
      dp[(size_t)(j0 + r) * DH + c] = s;
    }
  }
}

extern "C" void kernel_launch(void* const* d_in, const int* in_sizes, int n_in,
                              void* d_out, int out_size, void* d_ws, size_t ws_size,
                              hipStream_t stream) {
  const float* x   = (const float*)d_in[0];
  const float* Wq  = (const float*)d_in[1];
  const float* Wk  = (const float*)d_in[2];
  const float* Wvd = (const float*)d_in[3];
  const float* Wvu = (const float*)d_in[4];
  float* out = (float*)d_out;

  float* ws  = (float*)d_ws;
  float* cur = ws;                    // SQ*DE
  float* qA  = cur + SQ * DE;         // SQ*DH each
  float* kA  = qA + SQ * DH;
  float* vA  = kA + SQ * DH;
  float* qB  = vA + SQ * DH;
  float* kB  = qB + SQ * DH;
  float* vB  = kB + SQ * DH;
  float* WTq = vB + SQ * DH;          // NH*DE*DH each
  float* WTk = WTq + NH * DE * DH;
  float* WTv = WTk + NH * DE * DH;

  prep_kernel<<<4096, 256, 0, stream>>>(x, Wq, Wk, Wvd, cur, WTq, WTk, WTv);
  qkv0_kernel<<<SQ / NQ, 256, 0, stream>>>(x, WTq, WTk, WTv, qA, kA, vA);

  for (int h = 0; h < NH; h++) {
    const float* qi = (h & 1) ? qB : qA;
    const float* ki = (h & 1) ? kB : kA;
    const float* vi = (h & 1) ? vB : vA;
    float* qo = (h & 1) ? qA : qB;
    float* ko = (h & 1) ? kA : kB;
    float* vo = (h & 1) ? vA : vB;
    const size_t won = (size_t)(h + 1 < NH ? h + 1 : 0) * DE * DH;
    int flags = (h == NH - 1 ? 1 : 0) | (h < NH - 1 ? 2 : 0);
    fused_kernel<<<SQ / NQ, 256, 0, stream>>>(
        cur, qi, ki, vi, Wvu + (size_t)h * DE * DH,
        WTq + won, WTk + won, WTv + won, qo, ko, vo, out, flags);
  }
}

// Round 3
// 688.391 us; speedup vs baseline: 1.2854x; 1.0115x over previous
//
#include <hip/hip_runtime.h>
#include <math.h>

#define SQ 2048      // seq len
#define DE 512       // d_embedding
#define DH 64        // d_head
#define CW 128       // half-window
#define W2 256       // window width
#define NH 8         // heads
#define NQ 4         // queries per block
#define UW (W2 + NQ - 1)  // union window width = 259
#define NT 512       // threads per block
#define NW 8         // waves per block

// ---------------- prep: copy x -> cur, transpose Wq/Wk/Wvd to [h][e][c] ----------------
__global__ __launch_bounds__(256) void prep_kernel(
    const float* __restrict__ x, const float* __restrict__ Wq,
    const float* __restrict__ Wk, const float* __restrict__ Wvd,
    float* __restrict__ cur, float* __restrict__ WTq,
    float* __restrict__ WTk, float* __restrict__ WTv) {
  int i = blockIdx.x * 256 + threadIdx.x;
  if (i < SQ * DE) cur[i] = x[i];
  if (i < NH * DE * DH) {
    int c = i & 63;           // dh index
    int e = (i >> 6) & 511;   // embedding index
    int h = i >> 15;
    int src = (h * DH + c) * DE + e;
    WTq[i] = Wq[src];
    WTk[i] = Wk[src];
    WTv[i] = Wvd[src];
  }
}

// ---------------- qkv0: q/k/v for head 0 straight from x ----------------
// 512 blocks x 4 rows x 512 threads; waves split e-range, LDS reduce.
__global__ __launch_bounds__(NT, 4) void qkv0_kernel(
    const float* __restrict__ x,
    const float* __restrict__ WTq, const float* __restrict__ WTk,
    const float* __restrict__ WTv,
    float* __restrict__ q, float* __restrict__ k, float* __restrict__ v) {
  __shared__ float xL[NQ][DE];            // 8 KB
  __shared__ float qP[NW][3][NQ][DH];     // 24 KB
  int tid = threadIdx.x, lane = tid & 63, wv = tid >> 6;
  int j0 = blockIdx.x * NQ;

  ((float4*)xL)[tid] = ((const float4*)(x + (size_t)j0 * DE))[tid];
  __syncthreads();

  float aq[NQ] = {0, 0, 0, 0}, ak[NQ] = {0, 0, 0, 0}, av[NQ] = {0, 0, 0, 0};
  int e0 = wv * 64;
  for (int e = e0; e < e0 + 64; e++) {
    float wq = WTq[e * DH + lane];
    float wk = WTk[e * DH + lane];
    float wvv = WTv[e * DH + lane];
#pragma unroll
    for (int r = 0; r < NQ; r++) {
      float xr = xL[r][e];
      aq[r] += xr * wq; ak[r] += xr * wk; av[r] += xr * wvv;
    }
  }
#pragma unroll
  for (int r = 0; r < NQ; r++) {
    qP[wv][0][r][lane] = aq[r];
    qP[wv][1][r][lane] = ak[r];
    qP[wv][2][r][lane] = av[r];
  }
  __syncthreads();
  for (int i = tid; i < 3 * NQ * DH; i += NT) {
    int o = i >> 8;              // 0..2 (NQ*DH = 256)
    int rem = i & 255;
    int r = rem >> 6, c = rem & 63;
    float s = 0;
#pragma unroll
    for (int w = 0; w < NW; w++) s += qP[w][o][r][c];
    float* dp = (o == 0 ? q : (o == 1 ? k : v));
    dp[(size_t)(j0 + r) * DH + c] = s;
  }
}

// ---------------- fused: attn(head h) [+ qkv(head h+1)] ----------------
// flags bit0: last head -> write out = cur/8 ; bit1: compute next-head qkv
__global__ __launch_bounds__(NT, 4) void fused_kernel(
    float* __restrict__ cur,
    const float* __restrict__ q, const float* __restrict__ k,
    const float* __restrict__ v, const float* __restrict__ Wvu,
    const float* __restrict__ WTqn, const float* __restrict__ WTkn,
    const float* __restrict__ WTvn,
    float* __restrict__ qn, float* __restrict__ kn, float* __restrict__ vn,
    float* __restrict__ out, int flags) {
  __shared__ float qL[NQ][DH];            // 1 KB
  __shared__ float sL[NQ][W2];            // 4 KB
  __shared__ float pL[NW][NQ][DH];        // 8 KB
  __shared__ float dL[NQ][DH];            // 1 KB
  __shared__ float yL[NQ][DE];            // 8 KB (y, then new-cur)
  __shared__ float qP[NW][3][NQ][DH];     // 24 KB

  int tid = threadIdx.x, lane = tid & 63, wv = tid >> 6;
  int j0 = blockIdx.x * NQ;

  // load q rows (NQ*DH = 256 floats)
  if (tid < NQ * DH) ((float*)qL)[tid] = q[(size_t)j0 * DH + tid];
  __syncthreads();

  // ---- scores over union window: thread tid owns union offset tid ----
  if (tid < UW) {
    int goff = tid;
    int g = j0 - CW + goff;
    bool valid = (g >= 0 && g < SQ);
    int gc = valid ? g : 0;
    float acc[NQ] = {0, 0, 0, 0};
    const float4* krow = (const float4*)(k + (size_t)gc * DH);
#pragma unroll
    for (int ch = 0; ch < 16; ch++) {
      float4 kf = krow[ch];
#pragma unroll
      for (int r = 0; r < NQ; r++) {
        float4 qf = ((const float4*)qL[r])[ch];
        acc[r] += qf.x * kf.x + qf.y * kf.y + qf.z * kf.z + qf.w * kf.w;
      }
    }
#pragma unroll
    for (int r = 0; r < NQ; r++) {
      int p = goff - r;
      if (p >= 0 && p < W2) sL[r][p] = valid ? acc[r] * 0.125f : -INFINITY;
    }
  }
  __syncthreads();

  // ---- softmax: wave wv owns row wv (waves 4-7 idle; tiny phase) ----
  if (wv < NQ) {
    int r = wv;
    float m = -INFINITY;
#pragma unroll
    for (int t = 0; t < 4; t++) m = fmaxf(m, sL[r][lane + 64 * t]);
#pragma unroll
    for (int off = 32; off; off >>= 1) m = fmaxf(m, __shfl_xor(m, off));
    float ex[4], ss = 0;
#pragma unroll
    for (int t = 0; t < 4; t++) {
      ex[t] = __expf(sL[r][lane + 64 * t] - m);
      ss += ex[t];
    }
#pragma unroll
    for (int off = 32; off; off >>= 1) ss += __shfl_xor(ss, off);
    float inv = 1.0f / ss;
#pragma unroll
    for (int t = 0; t < 4; t++) sL[r][lane + 64 * t] = ex[t] * inv;
  }
  __syncthreads();

  // ---- delta = w . v_window ; 8 waves split union range; v loads coalesced ----
  {
    float dacc[NQ] = {0, 0, 0, 0};
    int gbeg = 33 * wv, gend = gbeg + 33;
    if (gend > UW) gend = UW;
    for (int goff = gbeg; goff < gend; goff++) {
      int g = j0 - CW + goff;
      int gc = g < 0 ? 0 : (g >= SQ ? SQ - 1 : g);
      float vv = v[(size_t)gc * DH + lane];
#pragma unroll
      for (int r = 0; r < NQ; r++) {
        int p = goff - r;
        if (p >= 0 && p < W2) dacc[r] += sL[r][p] * vv;
      }
    }
#pragma unroll
    for (int r = 0; r < NQ; r++) pL[wv][r][lane] = dacc[r];
  }
  __syncthreads();
  if (tid < NQ * DH) {
    int r = tid >> 6, c = tid & 63;
    float s = 0;
#pragma unroll
    for (int w = 0; w < NW; w++) s += pL[w][r][c];
    dL[r][c] = s;
  }
  __syncthreads();

  // ---- upproj + residual into yL: thread tid owns column e = tid ----
  {
    int e = tid;
    float acc[NQ] = {0, 0, 0, 0};
    const float4* wrow = (const float4*)(Wvu + (size_t)e * DH);
#pragma unroll
    for (int ch = 0; ch < 16; ch++) {
      float4 wf = wrow[ch];
#pragma unroll
      for (int r = 0; r < NQ; r++) {
        float4 df = ((const float4*)dL[r])[ch];
        acc[r] += df.x * wf.x + df.y * wf.y + df.z * wf.z + df.w * wf.w;
      }
    }
#pragma unroll
    for (int r = 0; r < NQ; r++)
      yL[r][e] = cur[(size_t)(j0 + r) * DE + e] + acc[r];
  }
  __syncthreads();

  // ---- renorm + residual update; wave wv owns row wv (waves 4-7 idle) ----
  if (wv < NQ) {
    int r = wv;
    size_t jrow = (size_t)(j0 + r) * DE;
    float s = 0;
#pragma unroll
    for (int t = 0; t < 8; t++) s += yL[r][lane + 64 * t];
#pragma unroll
    for (int off = 32; off; off >>= 1) s += __shfl_xor(s, off);
    float inv_m1 = 512.0f / s;  // 1/m1
    float y2[8], s2 = 0, s2q = 0;
#pragma unroll
    for (int t = 0; t < 8; t++) {
      y2[t] = yL[r][lane + 64 * t] * inv_m1;
      s2 += y2[t];
      s2q += y2[t] * y2[t];
    }
#pragma unroll
    for (int off = 32; off; off >>= 1) {
      s2 += __shfl_xor(s2, off);
      s2q += __shfl_xor(s2q, off);
    }
    float m2 = s2 * (1.0f / 512.0f);
    float var = (s2q - 512.0f * m2 * m2) * (1.0f / 511.0f);
    float isd = 1.0f / sqrtf(var);
#pragma unroll
    for (int t = 0; t < 8; t++) {
      int e = lane + 64 * t;
      float o = (y2[t] - m2) * isd + m2;
      float nc = cur[jrow + e] + o;
      cur[jrow + e] = nc;
      yL[r][e] = nc;  // new cur row for next-head qkv
      if (flags & 1) out[jrow + e] = nc * (1.0f / NH);
    }
  }
  __syncthreads();

  // ---- qkv for next head from LDS new-cur rows; 8 waves split e-range ----
  if (flags & 2) {
    float aq[NQ] = {0, 0, 0, 0}, ak[NQ] = {0, 0, 0, 0}, av[NQ] = {0, 0, 0, 0};
    int e0 = wv * 64;
    for (int e = e0; e < e0 + 64; e++) {
      float wq = WTqn[e * DH + lane];
      float wk = WTkn[e * DH + lane];
      float wvv = WTvn[e * DH + lane];
#pragma unroll
      for (int r = 0; r < NQ; r++) {
        float xr = yL[r][e];
        aq[r] += xr * wq; ak[r] += xr * wk; av[r] += xr * wvv;
      }
    }
#pragma unroll
    for (int r = 0; r < NQ; r++) {
      qP[wv][0][r][lane] = aq[r];
      qP[wv][1][r][lane] = ak[r];
      qP[wv][2][r][lane] = av[r];
    }
    __syncthreads();
    for (int i = tid; i < 3 * NQ * DH; i += NT) {
      int o = i >> 8;
      int rem = i & 255;
      int r = rem >> 6, c = rem & 63;
      float s = 0;
#pragma unroll
      for (int w = 0; w < NW; w++) s += qP[w][o][r][c];
      float* dp = (o == 0 ? qn : (o == 1 ? kn : vn));
      dp[(size_t)(j0 + r) * DH + c] = s;
    }
  }
}

extern "C" void kernel_launch(void* const* d_in, const int* in_sizes, int n_in,
                              void* d_out, int out_size, void* d_ws, size_t ws_size,
                              hipStream_t stream) {
  const float* x   = (const float*)d_in[0];
  const float* Wq  = (const float*)d_in[1];
  const float* Wk  = (const float*)d_in[2];
  const float* Wvd = (const float*)d_in[3];
  const float* Wvu = (const float*)d_in[4];
  float* out = (float*)d_out;

  float* ws  = (float*)d_ws;
  float* cur = ws;                    // SQ*DE
  float* qA  = cur + SQ * DE;         // SQ*DH each
  float* kA  = qA + SQ * DH;
  float* vA  = kA + SQ * DH;
  float* qB  = vA + SQ * DH;
  float* kB  = qB + SQ * DH;
  float* vB  = kB + SQ * DH;
  float* WTq = vB + SQ * DH;          // NH*DE*DH each
  float* WTk = WTq + NH * DE * DH;
  float* WTv = WTk + NH * DE * DH;

  prep_kernel<<<4096, 256, 0, stream>>>(x, Wq, Wk, Wvd, cur, WTq, WTk, WTv);
  qkv0_kernel<<<SQ / NQ, NT, 0, stream>>>(x, WTq, WTk, WTv, qA, kA, vA);

  for (int h = 0; h < NH; h++) {
    const float* qi = (h & 1) ? qB : qA;
    const float* ki = (h & 1) ? kB : kA;
    const float* vi = (h & 1) ? vB : vA;
    float* qo = (h & 1) ? qA : qB;
    float* ko = (h & 1) ? kA : kB;
    float* vo = (h & 1) ? vA : vB;
    const size_t won = (size_t)(h + 1 < NH ? h + 1 : 0) * DE * DH;
    int flags = (h == NH - 1 ? 1 : 0) | (h < NH - 1 ? 2 : 0);
    fused_kernel<<<SQ / NQ, NT, 0, stream>>>(
        cur, qi, ki, vi, Wvu + (size_t)h * DE * DH,
        WTq + won, WTk + won, WTv + won, qo, ko, vo, out, flags);
  }
}